// Round 1
// baseline (402.672 us; speedup 1.0000x reference)
//
#include <hip/hip_runtime.h>
#include <math.h>

#define NL 64
#define NB 7
#define EPS_ 0.02f
#define ITERS_ 200
#define TINY_ 1e-40f

__global__ __launch_bounds__(64) void sinkhorn_kernel(
    const float* __restrict__ theta,  // [L,B]
    const float* __restrict__ phi,    // [B]
    const float* __restrict__ n,      // [L]
    const float* __restrict__ sens,   // [L]
    const float* __restrict__ err,    // [B]
    float* __restrict__ out)          // [L,B]
{
    const int i = threadIdx.x;  // lane == row (exactly one wave of 64)

    // ---- load per-row data ----
    const float ni = n[i];
    const float si = sens[i];

    float K[NB];
    float phiv[NB];
    #pragma unroll
    for (int j = 0; j < NB; ++j) {
        const float ej = err[j];
        phiv[j] = phi[j];
        // K = -(C - theta)/EPS,  C = n*sens*err
        K[j] = -(ni * si * ej - theta[i * NB + j]) / EPS_;
    }

    // ---- row marginal: a = n / sum(n); log_a = log(a + TINY) ----
    float nsum = ni;
    #pragma unroll
    for (int d = 32; d >= 1; d >>= 1) nsum += __shfl_xor(nsum, d, 64);
    const float log_a = __logf(ni / nsum + TINY_);

    // ---- col marginal: b = softmax(phi); log_b = log(b + TINY) (redundant per lane) ----
    float pmax = phiv[0];
    #pragma unroll
    for (int j = 1; j < NB; ++j) pmax = fmaxf(pmax, phiv[j]);
    float psum = 0.f;
    #pragma unroll
    for (int j = 0; j < NB; ++j) psum += __expf(phiv[j] - pmax);
    const float logpsum = __logf(psum);
    float log_b[NB];
    #pragma unroll
    for (int j = 0; j < NB; ++j)
        log_b[j] = __logf(__expf(phiv[j] - pmax - logpsum) + TINY_);

    // ---- Sinkhorn iterations ----
    float f = 0.f;
    float g[NB];
    #pragma unroll
    for (int j = 0; j < NB; ++j) g[j] = 0.f;

    for (int it = 0; it < ITERS_; ++it) {
        // f = log_a - lse_j(K[i][j] + g[j])   (lane-local over 7 regs)
        float m = K[0] + g[0];
        #pragma unroll
        for (int j = 1; j < NB; ++j) m = fmaxf(m, K[j] + g[j]);
        float s = 0.f;
        #pragma unroll
        for (int j = 0; j < NB; ++j) s += __expf(K[j] + g[j] - m);
        f = log_a - (m + __logf(s));

        // g[j] = log_b[j] - lse_i(K[i][j] + f[i])   (64-lane butterfly per column)
        #pragma unroll
        for (int j = 0; j < NB; ++j) {
            const float v = K[j] + f;
            float mm = v;
            #pragma unroll
            for (int d = 32; d >= 1; d >>= 1) mm = fmaxf(mm, __shfl_xor(mm, d, 64));
            float e = __expf(v - mm);
            #pragma unroll
            for (int d = 32; d >= 1; d >>= 1) e += __shfl_xor(e, d, 64);
            g[j] = log_b[j] - (mm + __logf(e));
        }
    }

    // ---- P = exp(K + f + g); out = P / (P.sum() + TINY) ----
    // Shift by global max for stability; normalization cancels the shift.
    float x[NB];
    float m = -INFINITY;
    #pragma unroll
    for (int j = 0; j < NB; ++j) {
        x[j] = K[j] + f + g[j];
        m = fmaxf(m, x[j]);
    }
    #pragma unroll
    for (int d = 32; d >= 1; d >>= 1) m = fmaxf(m, __shfl_xor(m, d, 64));

    float p[NB];
    float s = 0.f;
    #pragma unroll
    for (int j = 0; j < NB; ++j) {
        p[j] = __expf(x[j] - m);
        s += p[j];
    }
    #pragma unroll
    for (int d = 32; d >= 1; d >>= 1) s += __shfl_xor(s, d, 64);

    // denom = sum(exp(x-m)) + TINY*exp(-m)  (== (P.sum() + TINY) * exp(-m))
    const float denom = s + TINY_ * __expf(-m);
    const float inv = 1.0f / denom;

    #pragma unroll
    for (int j = 0; j < NB; ++j)
        out[i * NB + j] = p[j] * inv;
}

extern "C" void kernel_launch(void* const* d_in, const int* in_sizes, int n_in,
                              void* d_out, int out_size, void* d_ws, size_t ws_size,
                              hipStream_t stream) {
    const float* theta = (const float*)d_in[0];  // [64,7]
    const float* phi   = (const float*)d_in[1];  // [7]
    const float* n     = (const float*)d_in[2];  // [64]
    const float* sens  = (const float*)d_in[3];  // [64]
    const float* err   = (const float*)d_in[4];  // [7]
    float* out = (float*)d_out;                  // [64,7]

    sinkhorn_kernel<<<1, 64, 0, stream>>>(theta, phi, n, sens, err, out);
}

// Round 2
// 236.588 us; speedup vs baseline: 1.7020x; 1.7020x over previous
//
#include <hip/hip_runtime.h>
#include <math.h>

#define NL 64
#define NB 7
#define EPS_ 0.02f
#define ITERS_ 200
#define TINY_ 1e-40f

// ---- DPP helpers (CDNA keeps GCN row_shr / row_bcast controls) ----
// update_dpp(old, src, ctrl, row_mask, bank_mask, bound_ctrl=false):
// lanes whose source is invalid keep `old` -> pass the reduction identity.
template <int CTRL>
__device__ __forceinline__ float dpp_ident(float identity, float x) {
    return __int_as_float(__builtin_amdgcn_update_dpp(
        __float_as_int(identity), __float_as_int(x), CTRL, 0xF, 0xF, false));
}

// Full 64-lane max, result broadcast to all lanes (VALU-only + readlane).
__device__ __forceinline__ float wave_max_bcast(float m) {
    const float NI = __int_as_float(0xff800000);  // -inf
    m = fmaxf(m, dpp_ident<0x111>(NI, m));  // row_shr:1
    m = fmaxf(m, dpp_ident<0x112>(NI, m));  // row_shr:2
    m = fmaxf(m, dpp_ident<0x114>(NI, m));  // row_shr:4
    m = fmaxf(m, dpp_ident<0x118>(NI, m));  // row_shr:8  -> lanes 15/31/47/63 have row totals
    m = fmaxf(m, dpp_ident<0x142>(NI, m));  // row_bcast:15 -> lane 31/63 combine pairs
    m = fmaxf(m, dpp_ident<0x143>(NI, m));  // row_bcast:31 -> lane 63 has all 64
    return __int_as_float(__builtin_amdgcn_readlane(__float_as_int(m), 63));
}

// Full 64-lane sum, result broadcast to all lanes.
__device__ __forceinline__ float wave_sum_bcast(float s) {
    s += dpp_ident<0x111>(0.f, s);
    s += dpp_ident<0x112>(0.f, s);
    s += dpp_ident<0x114>(0.f, s);
    s += dpp_ident<0x118>(0.f, s);
    s += dpp_ident<0x142>(0.f, s);
    s += dpp_ident<0x143>(0.f, s);
    return __int_as_float(__builtin_amdgcn_readlane(__float_as_int(s), 63));
}

__global__ __launch_bounds__(64) void sinkhorn_kernel(
    const float* __restrict__ theta,  // [L,B]
    const float* __restrict__ phi,    // [B]
    const float* __restrict__ n,      // [L]
    const float* __restrict__ sens,   // [L]
    const float* __restrict__ err,    // [B]
    float* __restrict__ out)          // [L,B]
{
    const int i = threadIdx.x;  // lane == row (exactly one wave of 64)

    const float ni = n[i];
    const float si = sens[i];

    float K[NB];
    float phiv[NB];
    #pragma unroll
    for (int j = 0; j < NB; ++j) {
        phiv[j] = phi[j];
        K[j] = -(ni * si * err[j] - theta[i * NB + j]) / EPS_;
    }

    // ---- row marginal: log_a = log(n/sum(n) + TINY) ----
    const float nsum = wave_sum_bcast(ni);
    const float log_a = __logf(ni / nsum + TINY_);

    // ---- col marginal: log_b = log(softmax(phi) + TINY) (computed per lane) ----
    float pmax = phiv[0];
    #pragma unroll
    for (int j = 1; j < NB; ++j) pmax = fmaxf(pmax, phiv[j]);
    float psum = 0.f;
    #pragma unroll
    for (int j = 0; j < NB; ++j) psum += __expf(phiv[j] - pmax);
    const float logpsum = __logf(psum);
    float log_b[NB];
    #pragma unroll
    for (int j = 0; j < NB; ++j)
        log_b[j] = __logf(__expf(phiv[j] - pmax - logpsum) + TINY_);

    // ---- Sinkhorn iterations with bitwise fixed-point early exit ----
    // g is wave-uniform (produced via readlane); once g_new == g_old bitwise,
    // the deterministic iteration map is idempotent -> breaking is exact.
    float f = 0.f;
    float g[NB];
    #pragma unroll
    for (int j = 0; j < NB; ++j) g[j] = 0.f;

    for (int it = 0; it < ITERS_; ++it) {
        // f = log_a - lse_j(K[j] + g[j])   (lane-local over 7 regs)
        float m = K[0] + g[0];
        #pragma unroll
        for (int j = 1; j < NB; ++j) m = fmaxf(m, K[j] + g[j]);
        float s = 0.f;
        #pragma unroll
        for (int j = 0; j < NB; ++j) s += __expf(K[j] + g[j] - m);
        f = log_a - (m + __logf(s));

        // g[j] = log_b[j] - lse_i(K[i][j] + f[i])   (64-lane DPP reductions;
        // 7 independent column chains interleave in the VALU pipe)
        float gn[NB];
        #pragma unroll
        for (int j = 0; j < NB; ++j) {
            const float v = K[j] + f;
            const float mm = wave_max_bcast(v);
            const float e = __expf(v - mm);
            const float ss = wave_sum_bcast(e);
            gn[j] = log_b[j] - (mm + __logf(ss));
        }

        bool same = true;
        #pragma unroll
        for (int j = 0; j < NB; ++j) {
            same = same && (gn[j] == g[j]);
            g[j] = gn[j];
        }
        if (same) break;  // wave-uniform branch, exact (idempotent fixed point)
    }

    // ---- P = exp(K + f + g); out = P / (P.sum() + TINY) ----
    float x[NB];
    float m = -INFINITY;
    #pragma unroll
    for (int j = 0; j < NB; ++j) {
        x[j] = K[j] + f + g[j];
        m = fmaxf(m, x[j]);
    }
    m = wave_max_bcast(m);

    float p[NB];
    float s = 0.f;
    #pragma unroll
    for (int j = 0; j < NB; ++j) {
        p[j] = __expf(x[j] - m);
        s += p[j];
    }
    s = wave_sum_bcast(s);

    // denom = (P.sum() + TINY) * exp(-m), computed in shifted domain
    const float inv = 1.0f / (s + TINY_ * __expf(-m));

    #pragma unroll
    for (int j = 0; j < NB; ++j)
        out[i * NB + j] = p[j] * inv;
}

extern "C" void kernel_launch(void* const* d_in, const int* in_sizes, int n_in,
                              void* d_out, int out_size, void* d_ws, size_t ws_size,
                              hipStream_t stream) {
    const float* theta = (const float*)d_in[0];  // [64,7]
    const float* phi   = (const float*)d_in[1];  // [7]
    const float* n     = (const float*)d_in[2];  // [64]
    const float* sens  = (const float*)d_in[3];  // [64]
    const float* err   = (const float*)d_in[4];  // [7]
    float* out = (float*)d_out;                  // [64,7]

    sinkhorn_kernel<<<1, 64, 0, stream>>>(theta, phi, n, sens, err, out);
}